// Round 10
// baseline (402.055 us; speedup 1.0000x reference)
//
#include <hip/hip_runtime.h>
#include <hip/hip_bf16.h>
#include <math.h>

#define T_   4096
#define B_   4
#define C_   256
#define C3_  768
#define H_   1024
#define E_   4
#define M_   (B_*T_)      // 16384 rows
#define NCH_ 64
#define CHL_ (T_/NCH_)    // 64
#define KH_  4096         // E*H

typedef __attribute__((ext_vector_type(8))) short short8;
typedef __attribute__((ext_vector_type(4))) float floatx4;

__device__ __forceinline__ float b2f(unsigned short u) {
  union { unsigned int i; float f; } x; x.i = ((unsigned int)u) << 16; return x.f;
}
__device__ __forceinline__ unsigned short f2b(float f) {
  __hip_bfloat16 h = __float2bfloat16(f);
  return *reinterpret_cast<unsigned short*>(&h);
}
__device__ __forceinline__ void unpack8(uint4 a, float* f) {
  unsigned int w[4] = {a.x, a.y, a.z, a.w};
  #pragma unroll
  for (int i = 0; i < 4; i++) {
    union { unsigned int u; float g; } lo, hi;
    lo.u = w[i] << 16; hi.u = w[i] & 0xffff0000u;
    f[2*i] = lo.g; f[2*i+1] = hi.g;
  }
}
__device__ __forceinline__ void gl_lds16(const void* g, void* l) {
  __builtin_amdgcn_global_load_lds(
      (const __attribute__((address_space(1))) void*)g,
      (__attribute__((address_space(3))) void*)l, 16, 0, 0);
}
// sigmoid GELU: x*sigma(1.702x). |err|<=~0.01 on hid; enters out via zero-mean w2 sum.
__device__ __forceinline__ float gelu_s(float v) {
  float e = __expf(-1.702f * v);
  return v * __builtin_amdgcn_rcpf(1.0f + e);
}
// pack 4 floats -> 4 fp8 e4m3 (OCP) in one uint
__device__ __forceinline__ unsigned int pk_fp8x4(float a, float b, float c, float d) {
  unsigned int v = 0;
  v = __builtin_amdgcn_cvt_pk_fp8_f32(a, b, v, false);
  v = __builtin_amdgcn_cvt_pk_fp8_f32(c, d, v, true);
  return v;
}
__device__ __forceinline__ unsigned char f2fp8(float v) {
  return (unsigned char)(__builtin_amdgcn_cvt_pk_fp8_f32(v, v, 0, false) & 0xff);
}

// ---------------- transpose + fp32->bf16: src[K,N](+z*K*N) -> dst[+z*zStr][n*dstLd + k] ----
__global__ __launch_bounds__(256) void transpose_cvt(
    const float* __restrict__ src, unsigned short* __restrict__ dst, int K, int N,
    int dstLd, size_t dstZStride) {
  __shared__ float tile[32][33];
  src += (size_t)blockIdx.z * K * N;
  dst += (size_t)blockIdx.z * dstZStride;
  int n0 = blockIdx.x * 32, k0 = blockIdx.y * 32;
  int tx = threadIdx.x, ty = threadIdx.y;   // blockDim (32,8)
  #pragma unroll
  for (int i = 0; i < 32; i += 8)
    tile[ty + i][tx] = src[(size_t)(k0 + ty + i) * N + n0 + tx];
  __syncthreads();
  #pragma unroll
  for (int i = 0; i < 32; i += 8)
    dst[(size_t)(n0 + ty + i) * dstLd + k0 + tx] = f2b(tile[tx][ty + i]);
}

// ---------------- w2 -> fp8: w2f8[c][perm(e*1024+h)] = fp8(w2[e][h][c] * 256) ----------
__global__ __launch_bounds__(256) void transpose_w2_fp8(
    const float* __restrict__ src, unsigned char* __restrict__ dst) {
  __shared__ float tile[32][33];
  int e = blockIdx.z;
  src += (size_t)e * H_ * C_;
  int h0 = blockIdx.x * 32, c0 = blockIdx.y * 32;
  int tx = threadIdx.x, ty = threadIdx.y;
  #pragma unroll
  for (int i = 0; i < 32; i += 8)
    tile[ty + i][tx] = src[(size_t)(h0 + ty + i) * C_ + c0 + tx];
  __syncthreads();
  int k = e * H_ + h0 + tx;
  int kp = (k & ~63) | ((k & 48) >> 2) | ((k & 12) << 2) | (k & 3);
  #pragma unroll
  for (int i = 0; i < 32; i += 8)
    dst[(size_t)(c0 + ty + i) * KH_ + kp] = f2fp8(tile[tx][ty + i] * 256.0f);
}

// ---------------- LayerNorm 1 ----------------
__global__ __launch_bounds__(256) void ln1_kernel(
    const float* __restrict__ x, const float* __restrict__ g,
    const float* __restrict__ b, unsigned short* __restrict__ h) {
  __shared__ float red[4];
  int row = blockIdx.x, tid = threadIdx.x;
  float v = x[(size_t)row * C_ + tid];
  float s = v;
  #pragma unroll
  for (int o = 32; o; o >>= 1) s += __shfl_xor(s, o);
  if ((tid & 63) == 0) red[tid >> 6] = s;
  __syncthreads();
  float mean = (red[0] + red[1] + red[2] + red[3]) * (1.0f / C_);
  __syncthreads();
  float d = v - mean;
  float q = d * d;
  #pragma unroll
  for (int o = 32; o; o >>= 1) q += __shfl_xor(q, o);
  if ((tid & 63) == 0) red[tid >> 6] = q;
  __syncthreads();
  float var = (red[0] + red[1] + red[2] + red[3]) * (1.0f / C_);
  h[(size_t)row * C_ + tid] = f2b(d * rsqrtf(var + 1e-5f) * g[tid] + b[tid]);
}

// ---------------- LayerNorm 2 + gating softmax (h2 bf16) ----------------
__global__ __launch_bounds__(256) void ln2_gates_kernel(
    const float* __restrict__ x1, const float* __restrict__ g,
    const float* __restrict__ b, const float* __restrict__ gw,
    const float* __restrict__ gb, unsigned short* __restrict__ h2,
    float* __restrict__ gates) {
  __shared__ float red[4];
  __shared__ float redg[4][4];
  int row = blockIdx.x, tid = threadIdx.x;
  float v = x1[(size_t)row * C_ + tid];
  float s = v;
  #pragma unroll
  for (int o = 32; o; o >>= 1) s += __shfl_xor(s, o);
  if ((tid & 63) == 0) red[tid >> 6] = s;
  __syncthreads();
  float mean = (red[0] + red[1] + red[2] + red[3]) * (1.0f / C_);
  __syncthreads();
  float d = v - mean;
  float q = d * d;
  #pragma unroll
  for (int o = 32; o; o >>= 1) q += __shfl_xor(q, o);
  if ((tid & 63) == 0) red[tid >> 6] = q;
  __syncthreads();
  float var = (red[0] + red[1] + red[2] + red[3]) * (1.0f / C_);
  float hv = d * rsqrtf(var + 1e-5f) * g[tid] + b[tid];
  h2[(size_t)row * C_ + tid] = f2b(hv);
  float p0 = hv * gw[tid * 4 + 0];
  float p1 = hv * gw[tid * 4 + 1];
  float p2 = hv * gw[tid * 4 + 2];
  float p3 = hv * gw[tid * 4 + 3];
  #pragma unroll
  for (int o = 32; o; o >>= 1) {
    p0 += __shfl_xor(p0, o); p1 += __shfl_xor(p1, o);
    p2 += __shfl_xor(p2, o); p3 += __shfl_xor(p3, o);
  }
  if ((tid & 63) == 0) {
    int w = tid >> 6;
    redg[w][0] = p0; redg[w][1] = p1; redg[w][2] = p2; redg[w][3] = p3;
  }
  __syncthreads();
  if (tid == 0) {
    float t4[4];
    #pragma unroll
    for (int e = 0; e < 4; e++)
      t4[e] = redg[0][e] + redg[1][e] + redg[2][e] + redg[3][e] + gb[e];
    float m = fmaxf(fmaxf(t4[0], t4[1]), fmaxf(t4[2], t4[3]));
    float zs = 0.f;
    #pragma unroll
    for (int e = 0; e < 4; e++) { t4[e] = __expf(t4[e] - m); zs += t4[e]; }
    float inv = 1.0f / zs;
    #pragma unroll
    for (int e = 0; e < 4; e++) gates[(size_t)row * 4 + e] = t4[e] * inv;
  }
}

// ---------------- chunked prefix scan of v ----------------
__global__ __launch_bounds__(256) void scan1_kernel(const unsigned short* __restrict__ qkv,
                                                    float* __restrict__ S) {
  int b = blockIdx.x >> 6, ch = blockIdx.x & 63, c = threadIdx.x;
  float s = 0.f;
  size_t base = ((size_t)b * T_ + (size_t)ch * CHL_) * C3_ + 512 + c;
  for (int t = 0; t < CHL_; t++) s += b2f(qkv[base + (size_t)t * C3_]);
  S[((size_t)b * NCH_ + ch) * C_ + c] = s;
}
__global__ __launch_bounds__(256) void scan2_kernel(float* __restrict__ S) {
  int b = blockIdx.x, c = threadIdx.x;
  float run = 0.f;
  for (int ch = 0; ch < NCH_; ch++) {
    size_t i = ((size_t)b * NCH_ + ch) * C_ + c;
    float t = S[i]; S[i] = run; run += t;
  }
}
__global__ __launch_bounds__(256) void scan3_kernel(const unsigned short* __restrict__ qkv,
                                                    const float* __restrict__ S,
                                                    unsigned short* __restrict__ Pb) {
  int b = blockIdx.x >> 6, ch = blockIdx.x & 63, c = threadIdx.x;
  float run = S[((size_t)b * NCH_ + ch) * C_ + c];
  size_t row0 = (size_t)b * T_ + (size_t)ch * CHL_;
  for (int t = 0; t < CHL_; t++) {
    run += b2f(qkv[(row0 + t) * C3_ + 512 + c]);
    Pb[(row0 + t) * C_ + c] = f2b(run);
  }
}

// ---------------- windowed attention: 16-lane group per window position ----------------
__global__ __launch_bounds__(256) void attn_kernel(
    const unsigned short* __restrict__ qkv, const unsigned short* __restrict__ Pb,
    const float* __restrict__ gate, unsigned short* __restrict__ aout) {
  int wave = threadIdx.x >> 6, lane = threadIdx.x & 63;
  int r = blockIdx.x * 4 + wave;
  int t = r & (T_ - 1);
  int g = lane >> 4, u = lane & 15;
  const unsigned short* qp = qkv + (size_t)r * C3_ + (u << 4);
  float qv[16];
  unpack8(*(const uint4*)qp, qv);
  unpack8(*(const uint4*)(qp + 8), qv + 8);
  float sc[5];
  #pragma unroll
  for (int rnd = 0; rnd < 5; rnd++) {
    int j = rnd * 4 + g;
    int jj = t - 16 + j;
    bool valid = (j <= 16) && (jj >= 0);
    float d = 0.f;
    if (valid) {
      const unsigned short* kp = qkv + (size_t)(r - 16 + j) * C3_ + 256 + (u << 4);
      float kv[16];
      unpack8(*(const uint4*)kp, kv);
      unpack8(*(const uint4*)(kp + 8), kv + 8);
      #pragma unroll
      for (int c = 0; c < 16; c++) d += qv[c] * kv[c];
    }
    d += __shfl_xor(d, 1); d += __shfl_xor(d, 2);
    d += __shfl_xor(d, 4); d += __shfl_xor(d, 8);
    sc[rnd] = valid ? d * 0.0625f : -1e30f;
  }
  float m = fmaxf(fmaxf(fmaxf(sc[0], sc[1]), fmaxf(sc[2], sc[3])), sc[4]);
  m = fmaxf(m, __shfl_xor(m, 16));
  m = fmaxf(m, __shfl_xor(m, 32));
  if (t > 16) m = fmaxf(m, 0.0f);
  float ev[5], Zp = 0.f;
  #pragma unroll
  for (int rnd = 0; rnd < 5; rnd++) {
    ev[rnd] = (sc[rnd] > -1e29f) ? __expf(sc[rnd] - m) : 0.f;
    Zp += ev[rnd];
  }
  Zp += __shfl_xor(Zp, 16);
  Zp += __shfl_xor(Zp, 32);
  float e0v = 0.f;
  if (t > 16) { e0v = __expf(-m); Zp += e0v * (float)(t - 16); }
  float vp[16];
  #pragma unroll
  for (int c = 0; c < 16; c++) vp[c] = 0.f;
  #pragma unroll
  for (int rnd = 0; rnd < 5; rnd++) {
    if (ev[rnd] != 0.f) {
      int j = rnd * 4 + g;
      const unsigned short* vpp = qkv + (size_t)(r - 16 + j) * C3_ + 512 + (u << 4);
      float vv[16];
      unpack8(*(const uint4*)vpp, vv);
      unpack8(*(const uint4*)(vpp + 8), vv + 8);
      #pragma unroll
      for (int c = 0; c < 16; c++) vp[c] += ev[rnd] * vv[c];
    }
  }
  #pragma unroll
  for (int c = 0; c < 16; c++) {
    vp[c] += __shfl_xor(vp[c], 16);
    vp[c] += __shfl_xor(vp[c], 32);
  }
  if (g == 0) {
    if (t > 16) {
      const unsigned short* pp = Pb + (size_t)(r - 17) * C_ + (u << 4);
      float pv[16];
      unpack8(*(const uint4*)pp, pv);
      unpack8(*(const uint4*)(pp + 8), pv + 8);
      #pragma unroll
      for (int c = 0; c < 16; c++) vp[c] += e0v * pv[c];
    }
    float inv = 1.0f / Zp;
    const float* gp = gate + (u << 4);
    unsigned int ow[8];
    #pragma unroll
    for (int i = 0; i < 8; i++) {
      unsigned short lo = f2b(vp[2*i] * inv * gp[2*i]);
      unsigned short hi = f2b(vp[2*i+1] * inv * gp[2*i+1]);
      ow[i] = (unsigned int)lo | ((unsigned int)hi << 16);
    }
    uint4 s0 = {ow[0], ow[1], ow[2], ow[3]};
    uint4 s1 = {ow[4], ow[5], ow[6], ow[7]};
    *(uint4*)(aout + (size_t)r * C_ + (u << 4)) = s0;
    *(uint4*)(aout + (size_t)r * C_ + (u << 4) + 8) = s1;
  }
}

// ---------------- 128x128 bf16 MFMA GEMM, operand-swapped, swizzled staging -------------
// EPI 0: outb = bf16(acc + bias)      (qkv)
// EPI 1: x1 = acc + bias + resid      (proj)
template<int EPI>
__global__ __launch_bounds__(256) void gemm128(
    const unsigned short* __restrict__ A, const unsigned short* __restrict__ Bt,
    const float* __restrict__ bias, int K, int ldOut,
    const float* __restrict__ resid, float* __restrict__ outf,
    unsigned short* __restrict__ outb) {
  __shared__ __align__(16) unsigned short As[128 * 64];
  __shared__ __align__(16) unsigned short Bs[128 * 64];
  const int tid = threadIdx.x;
  const int wave = tid >> 6, lane = tid & 63;
  const int mBlk = blockIdx.x * 128, nBlk = blockIdx.y * 128;
  const int wm = (wave >> 1) * 64, wn = (wave & 1) * 64;
  const int lm = lane & 15, lk = (lane >> 4) * 8;
  floatx4 acc[4][4];
  #pragma unroll
  for (int i = 0; i < 4; i++)
    #pragma unroll
    for (int j = 0; j < 4; j++) acc[i][j] = (floatx4){0.f, 0.f, 0.f, 0.f};

  for (int kt = 0; kt < K; kt += 64) {
    __syncthreads();
    #pragma unroll
    for (int i = 0; i < 4; i++) {
      int seg = i * 256 + tid;          // 16B segment index
      int row = seg >> 3, g = seg & 7;
      int gc = (g ^ (row & 7)) << 3;    // XOR-swizzle the GLOBAL column (LDS stays linear)
      gl_lds16(A + (size_t)(mBlk + row) * K + kt + gc, &As[seg * 8]);
      gl_lds16(Bt + (size_t)(nBlk + row) * K + kt + gc, &Bs[seg * 8]);
    }
    __syncthreads();
    #pragma unroll
    for (int kk = 0; kk < 64; kk += 32) {
      short8 mf[4], nf[4];
      #pragma unroll
      for (int j = 0; j < 4; j++) {
        int row = wm + j * 16 + lm;
        mf[j] = *(const short8*)&As[row * 64 + ((((kk + lk) >> 3) ^ (row & 7)) << 3)];
      }
      #pragma unroll
      for (int i = 0; i < 4; i++) {
        int row = wn + i * 16 + lm;
        nf[i] = *(const short8*)&Bs[row * 64 + ((((kk + lk) >> 3) ^ (row & 7)) << 3)];
      }
      #pragma unroll
      for (int i = 0; i < 4; i++)
        #pragma unroll
        for (int j = 0; j < 4; j++)
          acc[i][j] = __builtin_amdgcn_mfma_f32_16x16x32_bf16(nf[i], mf[j], acc[i][j], 0, 0, 0);
    }
  }
  const int lc = lane & 15, q4 = (lane >> 4) * 4;
  #pragma unroll
  for (int i = 0; i < 4; i++) {
    int n0 = nBlk + wn + i * 16 + q4;
    float4 bs = *(const float4*)&bias[n0];
    #pragma unroll
    for (int j = 0; j < 4; j++) {
      int m = mBlk + wm + j * 16 + lc;
      float v0 = acc[i][j][0] + bs.x, v1 = acc[i][j][1] + bs.y;
      float v2 = acc[i][j][2] + bs.z, v3 = acc[i][j][3] + bs.w;
      if (EPI == 0) {
        ushort4 o = {f2b(v0), f2b(v1), f2b(v2), f2b(v3)};
        *(ushort4*)&outb[(size_t)m * ldOut + n0] = o;
      } else {
        size_t idx = (size_t)m * ldOut + n0;
        float4 r = *(const float4*)&resid[idx];
        float4 o = {v0 + r.x, v1 + r.y, v2 + r.z, v3 + r.w};
        *(float4*)&outf[idx] = o;
      }
    }
  }
}

// ---------------- MoE up: 64-row A-tile in LDS (32 KB, 4 blk/CU), B from L2 with --------
// distance-1 register prefetch, no k-loop barriers. Block = 64 rows x expert.
// Wave tile 32m x 64n per n-chunk. hid8[m][perm(n)] = fp8(64*gate*gelu_s(acc+b1)).
__global__ __launch_bounds__(256, 4) void gemm_up(
    const unsigned short* __restrict__ A, const unsigned short* __restrict__ Bt,
    const float* __restrict__ b1, const float* __restrict__ gates,
    unsigned char* __restrict__ hid8) {
  __shared__ __align__(16) unsigned short As[64 * 256];   // 32 KB
  const int tid = threadIdx.x;
  const int wave = tid >> 6, lane = tid & 63;
  const int mBlk = blockIdx.x * 64;
  const int e = blockIdx.y;
  const int wm = (wave >> 1) * 32, wn = (wave & 1) * 64;
  const int lm = lane & 15, quad = lane >> 4, lk = quad * 8;

  // stage A once: 64 rows x 32 segs(16B), XOR-swizzle within 8-seg groups
  #pragma unroll
  for (int r = 0; r < 8; r++) {
    int seg = r * 256 + tid;
    int row = seg >> 5, s = seg & 31;
    int sp = (s & 24) | ((s & 7) ^ (row & 7));
    gl_lds16(A + (size_t)(mBlk + row) * C_ + sp * 8, &As[seg * 8]);
  }
  __syncthreads();   // only barrier in the kernel

  const unsigned short* w1e = Bt + (size_t)e * H_ * C_;
  const int q4 = quad * 4;

  #pragma unroll 1
  for (int nc = 0; nc < 8; nc++) {
    floatx4 acc[4][2];
    #pragma unroll
    for (int i = 0; i < 4; i++)
      #pragma unroll
      for (int j = 0; j < 2; j++) acc[i][j] = (floatx4){0.f, 0.f, 0.f, 0.f};
    const unsigned short* w1n = w1e + (size_t)(nc * 128 + wn) * C_;
    // distance-1 software pipeline on the L2-resident B fragments
    short8 nfa[4], nfb[4];
    #pragma unroll
    for (int i = 0; i < 4; i++)
      nfa[i] = *(const short8*)(w1n + (size_t)(i * 16 + lm) * C_ + lk);
    #pragma unroll
    for (int kk = 0; kk < 8; kk++) {
      short8* cur = (kk & 1) ? nfb : nfa;
      short8* nxt = (kk & 1) ? nfa : nfb;
      if (kk < 7) {
        #pragma unroll
        for (int i = 0; i < 4; i++)
          nxt[i] = *(const short8*)(w1n + (size_t)(i * 16 + lm) * C_ + (kk + 1) * 32 + lk);
      }
      short8 mf[2];
      #pragma unroll
      for (int j = 0; j < 2; j++) {
        int row = wm + j * 16 + lm;
        int s = (kk * 32 + lk) >> 3;
        int sp = (s & 24) | ((s & 7) ^ (row & 7));
        mf[j] = *(const short8*)&As[row * 256 + sp * 8];
      }
      #pragma unroll
      for (int i = 0; i < 4; i++)
        #pragma unroll
        for (int j = 0; j < 2; j++)
          acc[i][j] = __builtin_amdgcn_mfma_f32_16x16x32_bf16(cur[i], mf[j], acc[i][j], 0, 0, 0);
    }
    // epilogue: one permuted 16B store per m-subrow
    const int nbase = e * H_ + nc * 128 + wn;     // global k-index base of this 64-block
    #pragma unroll
    for (int j = 0; j < 2; j++) {
      int m = mBlk + wm + j * 16 + lm;
      float gs = 64.0f * gates[(size_t)m * E_ + e];
      unsigned int w[4];
      #pragma unroll
      for (int i = 0; i < 4; i++) {
        int n0 = nbase + i * 16 + q4;
        float4 bs = *(const float4*)&b1[n0];
        w[i] = pk_fp8x4(gs * gelu_s(acc[i][j][0] + bs.x),
                        gs * gelu_s(acc[i][j][1] + bs.y),
                        gs * gelu_s(acc[i][j][2] + bs.z),
                        gs * gelu_s(acc[i][j][3] + bs.w));
      }
      uint4 st = {w[0], w[1], w[2], w[3]};
      *(uint4*)&hid8[(size_t)m * KH_ + nbase + quad * 16] = st;
    }
  }
}

// ---------------- MoE down (fp8): 128m x 64n, BK=128, out = acc/2^14 + x1 + sum g*b2 ----
__global__ __launch_bounds__(256) void gemm_down(
    const unsigned char* __restrict__ hid8, const unsigned char* __restrict__ w2f8,
    const float* __restrict__ b2, const float* __restrict__ gates,
    const float* __restrict__ x1, float* __restrict__ out) {
  __shared__ __align__(16) unsigned char As[128 * 128];  // 16 KB
  __shared__ __align__(16) unsigned char Bs[64 * 128];   // 8 KB
  const int tid = threadIdx.x;
  const int wave = tid >> 6, lane = tid & 63;
  const int mBlk = blockIdx.x * 128, nBlk = blockIdx.y * 64;
  const int wm = wave * 32;
  const int lm = lane & 15, quad = lane >> 4;
  floatx4 acc[4][2];
  #pragma unroll
  for (int i = 0; i < 4; i++)
    #pragma unroll
    for (int j = 0; j < 2; j++) acc[i][j] = (floatx4){0.f, 0.f, 0.f, 0.f};

  for (int kt = 0; kt < KH_; kt += 128) {
    __syncthreads();
    #pragma unroll
    for (int r = 0; r < 4; r++) {
      int seg = r * 256 + tid;
      int row = seg >> 3, s = seg & 7;
      int sp = s ^ (row & 7);
      gl_lds16(hid8 + (size_t)(mBlk + row) * KH_ + kt + sp * 16, &As[seg * 16]);
    }
    #pragma unroll
    for (int r = 0; r < 2; r++) {
      int seg = r * 256 + tid;
      int row = seg >> 3, s = seg & 7;
      int sp = s ^ (row & 7);
      gl_lds16(w2f8 + (size_t)(nBlk + row) * KH_ + kt + sp * 16, &Bs[seg * 16]);
    }
    __syncthreads();
    #pragma unroll
    for (int kk = 0; kk < 4; kk++) {
      int c8 = kk * 4 + quad;
      int s = c8 >> 1, h8 = (c8 & 1) * 8;
      long mf[2], nf[4];
      #pragma unroll
      for (int j = 0; j < 2; j++) {
        int row = wm + j * 16 + lm;
        mf[j] = *(const long*)&As[row * 128 + ((s ^ (row & 7)) << 4) + h8];
      }
      #pragma unroll
      for (int i = 0; i < 4; i++) {
        int row = i * 16 + lm;
        nf[i] = *(const long*)&Bs[row * 128 + ((s ^ (row & 7)) << 4) + h8];
      }
      #pragma unroll
      for (int i = 0; i < 4; i++)
        #pragma unroll
        for (int j = 0; j < 2; j++)
          acc[i][j] = __builtin_amdgcn_mfma_f32_16x16x32_fp8_fp8(nf[i], mf[j], acc[i][j], 0, 0, 0);
    }
  }
  const float sc = 1.0f / 16384.0f;     // undo x64 * x256
  const int q4 = quad * 4;
  #pragma unroll
  for (int j = 0; j < 2; j++) {
    int m = mBlk + wm + j * 16 + lm;
    float4 g4 = *(const float4*)(gates + (size_t)m * 4);
    #pragma unroll
    for (int i = 0; i < 4; i++) {
      int n0 = nBlk + i * 16 + q4;
      float4 bA = *(const float4*)&b2[0 * C_ + n0];
      float4 bB = *(const float4*)&b2[1 * C_ + n0];
      float4 bC = *(const float4*)&b2[2 * C_ + n0];
      float4 bD = *(const float4*)&b2[3 * C_ + n0];
      size_t idx = (size_t)m * C_ + n0;
      float4 r = *(const float4*)&x1[idx];
      float4 o;
      o.x = acc[i][j][0]*sc + r.x + g4.x*bA.x + g4.y*bB.x + g4.z*bC.x + g4.w*bD.x;
      o.y = acc[i][j][1]*sc + r.y + g4.x*bA.y + g4.y*bB.y + g4.z*bC.y + g4.w*bD.y;
      o.z = acc[i][j][2]*sc + r.z + g4.x*bA.z + g4.y*bB.z + g4.z*bC.z + g4.w*bD.z;
      o.w = acc[i][j][3]*sc + r.w + g4.x*bA.w + g4.y*bB.w + g4.z*bC.w + g4.w*bD.w;
      *(float4*)&out[idx] = o;
    }
  }
}

extern "C" void kernel_launch(void* const* d_in, const int* in_sizes, int n_in,
                              void* d_out, int out_size, void* d_ws, size_t ws_size,
                              hipStream_t stream) {
  const float* x       = (const float*)d_in[0];
  const float* ln1_g   = (const float*)d_in[1];
  const float* ln1_b   = (const float*)d_in[2];
  const float* qkv_w   = (const float*)d_in[3];
  const float* qkv_b   = (const float*)d_in[4];
  const float* proj_w  = (const float*)d_in[5];
  const float* proj_b  = (const float*)d_in[6];
  const float* attn_g  = (const float*)d_in[7];
  const float* ln2_g   = (const float*)d_in[8];
  const float* ln2_b   = (const float*)d_in[9];
  const float* gat_w   = (const float*)d_in[10];
  const float* gat_b   = (const float*)d_in[11];
  const float* e_w1    = (const float*)d_in[12];
  const float* e_b1    = (const float*)d_in[13];
  const float* e_w2    = (const float*)d_in[14];
  const float* e_b2    = (const float*)d_in[15];
  float* out = (float*)d_out;

  char* p = (char*)d_ws;
  unsigned short* h    = (unsigned short*)p; p += (size_t)M_ * C_ * 2;      // 8 MB
  unsigned short* qkv  = (unsigned short*)p; p += (size_t)M_ * C3_ * 2;     // 24 MB
  unsigned short* Pb   = (unsigned short*)p; p += (size_t)M_ * C_ * 2;      // 8 MB
  unsigned short* aout = (unsigned short*)p; p += (size_t)M_ * C_ * 2;      // 8 MB
  float*          x1   = (float*)p;          p += (size_t)M_ * C_ * 4;      // 16 MB
  unsigned short* h2   = (unsigned short*)p; p += (size_t)M_ * C_ * 2;      // 8 MB
  float*          gts  = (float*)p;          p += (size_t)M_ * E_ * 4;      // 256 KB
  float*          S    = (float*)p;          p += (size_t)B_ * NCH_ * C_ * 4;
  unsigned short* wq   = (unsigned short*)p; p += (size_t)C3_ * C_ * 2;
  unsigned short* wp   = (unsigned short*)p; p += (size_t)C_ * C_ * 2;
  unsigned short* w1t  = (unsigned short*)p; p += (size_t)KH_ * C_ * 2;     // 2 MB [4096,256]
  unsigned char*  w2f8 = (unsigned char*)p;  p += (size_t)C_ * KH_;         // 1 MB [256,4096]
  unsigned char*  hid8 = (unsigned char*)p;  p += (size_t)M_ * KH_;         // 64 MB [M,4096]

  dim3 t32x8(32, 8);
  transpose_cvt<<<dim3(C3_/32, C_/32, 1), t32x8, 0, stream>>>(qkv_w, wq, C_, C3_, C_, 0);
  transpose_cvt<<<dim3(C_/32, C_/32, 1),  t32x8, 0, stream>>>(proj_w, wp, C_, C_, C_, 0);
  // w1t[e*1024 + hrow][c]  (flat [4096, 256]) bf16
  transpose_cvt<<<dim3(H_/32, C_/32, E_), t32x8, 0, stream>>>(e_w1, w1t, C_, H_, C_, (size_t)H_ * C_);
  // w2f8[c][perm(e*1024+h)] fp8 x256
  transpose_w2_fp8<<<dim3(H_/32, C_/32, E_), t32x8, 0, stream>>>(e_w2, w2f8);

  ln1_kernel<<<M_, 256, 0, stream>>>(x, ln1_g, ln1_b, h);
  gemm128<0><<<dim3(M_/128, C3_/128), 256, 0, stream>>>(h, wq, qkv_b, C_, C3_,
      nullptr, nullptr, qkv);
  scan1_kernel<<<B_*NCH_, 256, 0, stream>>>(qkv, S);
  scan2_kernel<<<B_, 256, 0, stream>>>(S);
  scan3_kernel<<<B_*NCH_, 256, 0, stream>>>(qkv, S, Pb);
  attn_kernel<<<M_/4, 256, 0, stream>>>(qkv, Pb, attn_g, aout);
  // x1 = x + aout @ proj_w + proj_b
  gemm128<1><<<dim3(M_/128, C_/128), 256, 0, stream>>>(aout, wp, proj_b, C_, C_,
      x, x1, nullptr);
  ln2_gates_kernel<<<M_, 256, 0, stream>>>(x1, ln2_g, ln2_b, gat_w, gat_b, h2, gts);
  // hid8 = fp8(64 * gate * gelu_s(h2 @ w1 + b1)), permuted columns
  gemm_up<<<dim3(M_/64, E_), 256, 0, stream>>>(h2, w1t, e_b1, gts, hid8);
  // out = hid8 @ w2f8 / 2^14 + x1 + sum_e gate_e*b2_e
  gemm_down<<<dim3(M_/128, C_/64), 256, 0, stream>>>(hid8, w2f8, e_b2, gts, x1, out);
}

// Round 11
// 323.053 us; speedup vs baseline: 1.2445x; 1.2445x over previous
//
#include <hip/hip_runtime.h>
#include <hip/hip_bf16.h>
#include <math.h>

#define T_   4096
#define B_   4
#define C_   256
#define C3_  768
#define H_   1024
#define E_   4
#define M_   (B_*T_)      // 16384 rows
#define NCH_ 64
#define CHL_ (T_/NCH_)    // 64
#define KH_  4096         // E*H

typedef __attribute__((ext_vector_type(8))) short short8;
typedef __attribute__((ext_vector_type(4))) float floatx4;

__device__ __forceinline__ float b2f(unsigned short u) {
  union { unsigned int i; float f; } x; x.i = ((unsigned int)u) << 16; return x.f;
}
__device__ __forceinline__ unsigned short f2b(float f) {
  __hip_bfloat16 h = __float2bfloat16(f);
  return *reinterpret_cast<unsigned short*>(&h);
}
__device__ __forceinline__ void unpack8(uint4 a, float* f) {
  unsigned int w[4] = {a.x, a.y, a.z, a.w};
  #pragma unroll
  for (int i = 0; i < 4; i++) {
    union { unsigned int u; float g; } lo, hi;
    lo.u = w[i] << 16; hi.u = w[i] & 0xffff0000u;
    f[2*i] = lo.g; f[2*i+1] = hi.g;
  }
}
__device__ __forceinline__ void gl_lds16(const void* g, void* l) {
  __builtin_amdgcn_global_load_lds(
      (const __attribute__((address_space(1))) void*)g,
      (__attribute__((address_space(3))) void*)l, 16, 0, 0);
}
// sigmoid GELU: x*sigma(1.702x). |err|<=~0.01 on hid; attenuated by zero-mean w2 down-sum.
// Numerics verified on HW: R8/R9 passed with absmax 0.03125 using this form.
__device__ __forceinline__ float gelu_s(float v) {
  float e = __expf(-1.702f * v);
  return v * __builtin_amdgcn_rcpf(1.0f + e);
}
// pack 4 floats -> 4 fp8 e4m3 (OCP) in one uint
__device__ __forceinline__ unsigned int pk_fp8x4(float a, float b, float c, float d) {
  unsigned int v = 0;
  v = __builtin_amdgcn_cvt_pk_fp8_f32(a, b, v, false);
  v = __builtin_amdgcn_cvt_pk_fp8_f32(c, d, v, true);
  return v;
}
__device__ __forceinline__ unsigned char f2fp8(float v) {
  return (unsigned char)(__builtin_amdgcn_cvt_pk_fp8_f32(v, v, 0, false) & 0xff);
}

// ---------------- transpose + fp32->bf16: src[K,N](+z*K*N) -> dst[+z*zStr][n*dstLd + k] ----
__global__ __launch_bounds__(256) void transpose_cvt(
    const float* __restrict__ src, unsigned short* __restrict__ dst, int K, int N,
    int dstLd, size_t dstZStride) {
  __shared__ float tile[32][33];
  src += (size_t)blockIdx.z * K * N;
  dst += (size_t)blockIdx.z * dstZStride;
  int n0 = blockIdx.x * 32, k0 = blockIdx.y * 32;
  int tx = threadIdx.x, ty = threadIdx.y;   // blockDim (32,8)
  #pragma unroll
  for (int i = 0; i < 32; i += 8)
    tile[ty + i][tx] = src[(size_t)(k0 + ty + i) * N + n0 + tx];
  __syncthreads();
  #pragma unroll
  for (int i = 0; i < 32; i += 8)
    dst[(size_t)(n0 + ty + i) * dstLd + k0 + tx] = f2b(tile[tx][ty + i]);
}

// ---------------- w2 -> fp8: w2f8[c][perm(e*1024+h)] = fp8(w2[e][h][c] * 256) ----------
__global__ __launch_bounds__(256) void transpose_w2_fp8(
    const float* __restrict__ src, unsigned char* __restrict__ dst) {
  __shared__ float tile[32][33];
  int e = blockIdx.z;
  src += (size_t)e * H_ * C_;
  int h0 = blockIdx.x * 32, c0 = blockIdx.y * 32;
  int tx = threadIdx.x, ty = threadIdx.y;
  #pragma unroll
  for (int i = 0; i < 32; i += 8)
    tile[ty + i][tx] = src[(size_t)(h0 + ty + i) * C_ + c0 + tx];
  __syncthreads();
  int k = e * H_ + h0 + tx;
  int kp = (k & ~63) | ((k & 48) >> 2) | ((k & 12) << 2) | (k & 3);
  #pragma unroll
  for (int i = 0; i < 32; i += 8)
    dst[(size_t)(c0 + ty + i) * KH_ + kp] = f2fp8(tile[tx][ty + i] * 256.0f);
}

// ---------------- LayerNorm 1 ----------------
__global__ __launch_bounds__(256) void ln1_kernel(
    const float* __restrict__ x, const float* __restrict__ g,
    const float* __restrict__ b, unsigned short* __restrict__ h) {
  __shared__ float red[4];
  int row = blockIdx.x, tid = threadIdx.x;
  float v = x[(size_t)row * C_ + tid];
  float s = v;
  #pragma unroll
  for (int o = 32; o; o >>= 1) s += __shfl_xor(s, o);
  if ((tid & 63) == 0) red[tid >> 6] = s;
  __syncthreads();
  float mean = (red[0] + red[1] + red[2] + red[3]) * (1.0f / C_);
  __syncthreads();
  float d = v - mean;
  float q = d * d;
  #pragma unroll
  for (int o = 32; o; o >>= 1) q += __shfl_xor(q, o);
  if ((tid & 63) == 0) red[tid >> 6] = q;
  __syncthreads();
  float var = (red[0] + red[1] + red[2] + red[3]) * (1.0f / C_);
  h[(size_t)row * C_ + tid] = f2b(d * rsqrtf(var + 1e-5f) * g[tid] + b[tid]);
}

// ---------------- LayerNorm 2 + gating softmax (h2 bf16) ----------------
__global__ __launch_bounds__(256) void ln2_gates_kernel(
    const float* __restrict__ x1, const float* __restrict__ g,
    const float* __restrict__ b, const float* __restrict__ gw,
    const float* __restrict__ gb, unsigned short* __restrict__ h2,
    float* __restrict__ gates) {
  __shared__ float red[4];
  __shared__ float redg[4][4];
  int row = blockIdx.x, tid = threadIdx.x;
  float v = x1[(size_t)row * C_ + tid];
  float s = v;
  #pragma unroll
  for (int o = 32; o; o >>= 1) s += __shfl_xor(s, o);
  if ((tid & 63) == 0) red[tid >> 6] = s;
  __syncthreads();
  float mean = (red[0] + red[1] + red[2] + red[3]) * (1.0f / C_);
  __syncthreads();
  float d = v - mean;
  float q = d * d;
  #pragma unroll
  for (int o = 32; o; o >>= 1) q += __shfl_xor(q, o);
  if ((tid & 63) == 0) red[tid >> 6] = q;
  __syncthreads();
  float var = (red[0] + red[1] + red[2] + red[3]) * (1.0f / C_);
  float hv = d * rsqrtf(var + 1e-5f) * g[tid] + b[tid];
  h2[(size_t)row * C_ + tid] = f2b(hv);
  float p0 = hv * gw[tid * 4 + 0];
  float p1 = hv * gw[tid * 4 + 1];
  float p2 = hv * gw[tid * 4 + 2];
  float p3 = hv * gw[tid * 4 + 3];
  #pragma unroll
  for (int o = 32; o; o >>= 1) {
    p0 += __shfl_xor(p0, o); p1 += __shfl_xor(p1, o);
    p2 += __shfl_xor(p2, o); p3 += __shfl_xor(p3, o);
  }
  if ((tid & 63) == 0) {
    int w = tid >> 6;
    redg[w][0] = p0; redg[w][1] = p1; redg[w][2] = p2; redg[w][3] = p3;
  }
  __syncthreads();
  if (tid == 0) {
    float t4[4];
    #pragma unroll
    for (int e = 0; e < 4; e++)
      t4[e] = redg[0][e] + redg[1][e] + redg[2][e] + redg[3][e] + gb[e];
    float m = fmaxf(fmaxf(t4[0], t4[1]), fmaxf(t4[2], t4[3]));
    float zs = 0.f;
    #pragma unroll
    for (int e = 0; e < 4; e++) { t4[e] = __expf(t4[e] - m); zs += t4[e]; }
    float inv = 1.0f / zs;
    #pragma unroll
    for (int e = 0; e < 4; e++) gates[(size_t)row * 4 + e] = t4[e] * inv;
  }
}

// ---------------- chunked prefix scan of v ----------------
__global__ __launch_bounds__(256) void scan1_kernel(const unsigned short* __restrict__ qkv,
                                                    float* __restrict__ S) {
  int b = blockIdx.x >> 6, ch = blockIdx.x & 63, c = threadIdx.x;
  float s = 0.f;
  size_t base = ((size_t)b * T_ + (size_t)ch * CHL_) * C3_ + 512 + c;
  for (int t = 0; t < CHL_; t++) s += b2f(qkv[base + (size_t)t * C3_]);
  S[((size_t)b * NCH_ + ch) * C_ + c] = s;
}
__global__ __launch_bounds__(256) void scan2_kernel(float* __restrict__ S) {
  int b = blockIdx.x, c = threadIdx.x;
  float run = 0.f;
  for (int ch = 0; ch < NCH_; ch++) {
    size_t i = ((size_t)b * NCH_ + ch) * C_ + c;
    float t = S[i]; S[i] = run; run += t;
  }
}
__global__ __launch_bounds__(256) void scan3_kernel(const unsigned short* __restrict__ qkv,
                                                    const float* __restrict__ S,
                                                    unsigned short* __restrict__ Pb) {
  int b = blockIdx.x >> 6, ch = blockIdx.x & 63, c = threadIdx.x;
  float run = S[((size_t)b * NCH_ + ch) * C_ + c];
  size_t row0 = (size_t)b * T_ + (size_t)ch * CHL_;
  for (int t = 0; t < CHL_; t++) {
    run += b2f(qkv[(row0 + t) * C3_ + 512 + c]);
    Pb[(row0 + t) * C_ + c] = f2b(run);
  }
}

// ---------------- windowed attention: 16-lane group per window position ----------------
__global__ __launch_bounds__(256) void attn_kernel(
    const unsigned short* __restrict__ qkv, const unsigned short* __restrict__ Pb,
    const float* __restrict__ gate, unsigned short* __restrict__ aout) {
  int wave = threadIdx.x >> 6, lane = threadIdx.x & 63;
  int r = blockIdx.x * 4 + wave;
  int t = r & (T_ - 1);
  int g = lane >> 4, u = lane & 15;
  const unsigned short* qp = qkv + (size_t)r * C3_ + (u << 4);
  float qv[16];
  unpack8(*(const uint4*)qp, qv);
  unpack8(*(const uint4*)(qp + 8), qv + 8);
  float sc[5];
  #pragma unroll
  for (int rnd = 0; rnd < 5; rnd++) {
    int j = rnd * 4 + g;
    int jj = t - 16 + j;
    bool valid = (j <= 16) && (jj >= 0);
    float d = 0.f;
    if (valid) {
      const unsigned short* kp = qkv + (size_t)(r - 16 + j) * C3_ + 256 + (u << 4);
      float kv[16];
      unpack8(*(const uint4*)kp, kv);
      unpack8(*(const uint4*)(kp + 8), kv + 8);
      #pragma unroll
      for (int c = 0; c < 16; c++) d += qv[c] * kv[c];
    }
    d += __shfl_xor(d, 1); d += __shfl_xor(d, 2);
    d += __shfl_xor(d, 4); d += __shfl_xor(d, 8);
    sc[rnd] = valid ? d * 0.0625f : -1e30f;
  }
  float m = fmaxf(fmaxf(fmaxf(sc[0], sc[1]), fmaxf(sc[2], sc[3])), sc[4]);
  m = fmaxf(m, __shfl_xor(m, 16));
  m = fmaxf(m, __shfl_xor(m, 32));
  if (t > 16) m = fmaxf(m, 0.0f);
  float ev[5], Zp = 0.f;
  #pragma unroll
  for (int rnd = 0; rnd < 5; rnd++) {
    ev[rnd] = (sc[rnd] > -1e29f) ? __expf(sc[rnd] - m) : 0.f;
    Zp += ev[rnd];
  }
  Zp += __shfl_xor(Zp, 16);
  Zp += __shfl_xor(Zp, 32);
  float e0v = 0.f;
  if (t > 16) { e0v = __expf(-m); Zp += e0v * (float)(t - 16); }
  float vp[16];
  #pragma unroll
  for (int c = 0; c < 16; c++) vp[c] = 0.f;
  #pragma unroll
  for (int rnd = 0; rnd < 5; rnd++) {
    if (ev[rnd] != 0.f) {
      int j = rnd * 4 + g;
      const unsigned short* vpp = qkv + (size_t)(r - 16 + j) * C3_ + 512 + (u << 4);
      float vv[16];
      unpack8(*(const uint4*)vpp, vv);
      unpack8(*(const uint4*)(vpp + 8), vv + 8);
      #pragma unroll
      for (int c = 0; c < 16; c++) vp[c] += ev[rnd] * vv[c];
    }
  }
  #pragma unroll
  for (int c = 0; c < 16; c++) {
    vp[c] += __shfl_xor(vp[c], 16);
    vp[c] += __shfl_xor(vp[c], 32);
  }
  if (g == 0) {
    if (t > 16) {
      const unsigned short* pp = Pb + (size_t)(r - 17) * C_ + (u << 4);
      float pv[16];
      unpack8(*(const uint4*)pp, pv);
      unpack8(*(const uint4*)(pp + 8), pv + 8);
      #pragma unroll
      for (int c = 0; c < 16; c++) vp[c] += e0v * pv[c];
    }
    float inv = 1.0f / Zp;
    const float* gp = gate + (u << 4);
    unsigned int ow[8];
    #pragma unroll
    for (int i = 0; i < 8; i++) {
      unsigned short lo = f2b(vp[2*i] * inv * gp[2*i]);
      unsigned short hi = f2b(vp[2*i+1] * inv * gp[2*i+1]);
      ow[i] = (unsigned int)lo | ((unsigned int)hi << 16);
    }
    uint4 s0 = {ow[0], ow[1], ow[2], ow[3]};
    uint4 s1 = {ow[4], ow[5], ow[6], ow[7]};
    *(uint4*)(aout + (size_t)r * C_ + (u << 4)) = s0;
    *(uint4*)(aout + (size_t)r * C_ + (u << 4) + 8) = s1;
  }
}

// ---------------- 128x128 MFMA GEMM, operand-swapped, swizzled staging ------------------
// EPI 0: outb = bf16(acc + bias)                              (qkv)
// EPI 1: x1 = acc + bias + resid                              (proj)
// EPI 2: hid8[m][perm(n)] = fp8(64 * gate * gelu_s(acc+bias)) — one 16B store per lane/j
template<int EPI>
__global__ __launch_bounds__(256) void gemm128(
    const unsigned short* __restrict__ A, const unsigned short* __restrict__ Bt,
    const float* __restrict__ bias, int K, int ldOut,
    const float* __restrict__ resid, float* __restrict__ outf,
    unsigned short* __restrict__ outb, unsigned char* __restrict__ outf8,
    const float* __restrict__ gates) {
  __shared__ __align__(16) unsigned short As[128 * 64];
  __shared__ __align__(16) unsigned short Bs[128 * 64];
  const int tid = threadIdx.x;
  const int wave = tid >> 6, lane = tid & 63;
  const int mBlk = blockIdx.x * 128, nBlk = blockIdx.y * 128;
  const int wm = (wave >> 1) * 64, wn = (wave & 1) * 64;
  const int lm = lane & 15, lk = (lane >> 4) * 8;
  floatx4 acc[4][4];
  #pragma unroll
  for (int i = 0; i < 4; i++)
    #pragma unroll
    for (int j = 0; j < 4; j++) acc[i][j] = (floatx4){0.f, 0.f, 0.f, 0.f};

  for (int kt = 0; kt < K; kt += 64) {
    __syncthreads();
    #pragma unroll
    for (int i = 0; i < 4; i++) {
      int seg = i * 256 + tid;          // 16B segment index
      int row = seg >> 3, g = seg & 7;
      int gc = (g ^ (row & 7)) << 3;    // XOR-swizzle the GLOBAL column (LDS stays linear)
      gl_lds16(A + (size_t)(mBlk + row) * K + kt + gc, &As[seg * 8]);
      gl_lds16(Bt + (size_t)(nBlk + row) * K + kt + gc, &Bs[seg * 8]);
    }
    __syncthreads();
    #pragma unroll
    for (int kk = 0; kk < 64; kk += 32) {
      short8 mf[4], nf[4];
      #pragma unroll
      for (int j = 0; j < 4; j++) {
        int row = wm + j * 16 + lm;
        mf[j] = *(const short8*)&As[row * 64 + ((((kk + lk) >> 3) ^ (row & 7)) << 3)];
      }
      #pragma unroll
      for (int i = 0; i < 4; i++) {
        int row = wn + i * 16 + lm;
        nf[i] = *(const short8*)&Bs[row * 64 + ((((kk + lk) >> 3) ^ (row & 7)) << 3)];
      }
      #pragma unroll
      for (int i = 0; i < 4; i++)
        #pragma unroll
        for (int j = 0; j < 4; j++)
          acc[i][j] = __builtin_amdgcn_mfma_f32_16x16x32_bf16(nf[i], mf[j], acc[i][j], 0, 0, 0);
    }
  }
  const int lc = lane & 15, quad = lane >> 4, q4 = quad * 4;
  if (EPI == 2) {
    const int eIdx = nBlk >> 10;        // expert of this 128-col tile
    #pragma unroll
    for (int j = 0; j < 4; j++) {
      int m = mBlk + wm + j * 16 + lc;
      float gs = 64.0f * gates[(size_t)m * E_ + eIdx];
      unsigned int w[4];
      #pragma unroll
      for (int i = 0; i < 4; i++) {
        int n0 = nBlk + wn + i * 16 + q4;
        float4 bs = *(const float4*)&bias[n0];
        w[i] = pk_fp8x4(gs * gelu_s(acc[i][j][0] + bs.x),
                        gs * gelu_s(acc[i][j][1] + bs.y),
                        gs * gelu_s(acc[i][j][2] + bs.z),
                        gs * gelu_s(acc[i][j][3] + bs.w));
      }
      uint4 st = {w[0], w[1], w[2], w[3]};
      // permuted layout: byte p (within 64-block) = quad*16 + i*4 + r
      *(uint4*)&outf8[(size_t)m * KH_ + nBlk + wn + quad * 16] = st;
    }
  } else {
    #pragma unroll
    for (int i = 0; i < 4; i++) {
      int n0 = nBlk + wn + i * 16 + q4;
      float4 bs = *(const float4*)&bias[n0];
      #pragma unroll
      for (int j = 0; j < 4; j++) {
        int m = mBlk + wm + j * 16 + lc;
        float v0 = acc[i][j][0] + bs.x, v1 = acc[i][j][1] + bs.y;
        float v2 = acc[i][j][2] + bs.z, v3 = acc[i][j][3] + bs.w;
        if (EPI == 0) {
          ushort4 o = {f2b(v0), f2b(v1), f2b(v2), f2b(v3)};
          *(ushort4*)&outb[(size_t)m * ldOut + n0] = o;
        } else {
          size_t idx = (size_t)m * ldOut + n0;
          float4 r = *(const float4*)&resid[idx];
          float4 o = {v0 + r.x, v1 + r.y, v2 + r.z, v3 + r.w};
          *(float4*)&outf[idx] = o;
        }
      }
    }
  }
}

// ---------------- MoE down (fp8): 128m x 64n, BK=128, out = acc/2^14 + x1 + sum g*b2 ----
// hid8 [M, 4096] fp8 (x64, permuted cols); w2f8 [256, 4096] fp8 (x256, same perm).
__global__ __launch_bounds__(256) void gemm_down(
    const unsigned char* __restrict__ hid8, const unsigned char* __restrict__ w2f8,
    const float* __restrict__ b2, const float* __restrict__ gates,
    const float* __restrict__ x1, float* __restrict__ out) {
  __shared__ __align__(16) unsigned char As[128 * 128];  // 16 KB
  __shared__ __align__(16) unsigned char Bs[64 * 128];   // 8 KB
  const int tid = threadIdx.x;
  const int wave = tid >> 6, lane = tid & 63;
  const int mBlk = blockIdx.x * 128, nBlk = blockIdx.y * 64;
  const int wm = wave * 32;
  const int lm = lane & 15, quad = lane >> 4;
  floatx4 acc[4][2];
  #pragma unroll
  for (int i = 0; i < 4; i++)
    #pragma unroll
    for (int j = 0; j < 2; j++) acc[i][j] = (floatx4){0.f, 0.f, 0.f, 0.f};

  for (int kt = 0; kt < KH_; kt += 128) {
    __syncthreads();
    #pragma unroll
    for (int r = 0; r < 4; r++) {       // A: 128 rows x 8 segs(16B)
      int seg = r * 256 + tid;
      int row = seg >> 3, s = seg & 7;
      int sp = s ^ (row & 7);
      gl_lds16(hid8 + (size_t)(mBlk + row) * KH_ + kt + sp * 16, &As[seg * 16]);
    }
    #pragma unroll
    for (int r = 0; r < 2; r++) {       // B: 64 rows x 8 segs
      int seg = r * 256 + tid;
      int row = seg >> 3, s = seg & 7;
      int sp = s ^ (row & 7);
      gl_lds16(w2f8 + (size_t)(nBlk + row) * KH_ + kt + sp * 16, &Bs[seg * 16]);
    }
    __syncthreads();
    #pragma unroll
    for (int kk = 0; kk < 4; kk++) {    // 4 ksteps of 32 fp8
      int c8 = kk * 4 + quad;           // 8-byte chunk index in row
      int s = c8 >> 1, h8 = (c8 & 1) * 8;
      long mf[2], nf[4];
      #pragma unroll
      for (int j = 0; j < 2; j++) {
        int row = wm + j * 16 + lm;
        mf[j] = *(const long*)&As[row * 128 + ((s ^ (row & 7)) << 4) + h8];
      }
      #pragma unroll
      for (int i = 0; i < 4; i++) {
        int row = i * 16 + lm;
        nf[i] = *(const long*)&Bs[row * 128 + ((s ^ (row & 7)) << 4) + h8];
      }
      #pragma unroll
      for (int i = 0; i < 4; i++)
        #pragma unroll
        for (int j = 0; j < 2; j++)
          acc[i][j] = __builtin_amdgcn_mfma_f32_16x16x32_fp8_fp8(nf[i], mf[j], acc[i][j], 0, 0, 0);
    }
  }
  const float sc = 1.0f / 16384.0f;     // undo x64 * x256
  const int q4 = quad * 4;
  #pragma unroll
  for (int j = 0; j < 2; j++) {
    int m = mBlk + wm + j * 16 + lm;
    float4 g4 = *(const float4*)(gates + (size_t)m * 4);
    #pragma unroll
    for (int i = 0; i < 4; i++) {
      int n0 = nBlk + i * 16 + q4;
      float4 bA = *(const float4*)&b2[0 * C_ + n0];
      float4 bB = *(const float4*)&b2[1 * C_ + n0];
      float4 bC = *(const float4*)&b2[2 * C_ + n0];
      float4 bD = *(const float4*)&b2[3 * C_ + n0];
      size_t idx = (size_t)m * C_ + n0;
      float4 r = *(const float4*)&x1[idx];
      float4 o;
      o.x = acc[i][j][0]*sc + r.x + g4.x*bA.x + g4.y*bB.x + g4.z*bC.x + g4.w*bD.x;
      o.y = acc[i][j][1]*sc + r.y + g4.x*bA.y + g4.y*bB.y + g4.z*bC.y + g4.w*bD.y;
      o.z = acc[i][j][2]*sc + r.z + g4.x*bA.z + g4.y*bB.z + g4.z*bC.z + g4.w*bD.z;
      o.w = acc[i][j][3]*sc + r.w + g4.x*bA.w + g4.y*bB.w + g4.z*bC.w + g4.w*bD.w;
      *(float4*)&out[idx] = o;
    }
  }
}

extern "C" void kernel_launch(void* const* d_in, const int* in_sizes, int n_in,
                              void* d_out, int out_size, void* d_ws, size_t ws_size,
                              hipStream_t stream) {
  const float* x       = (const float*)d_in[0];
  const float* ln1_g   = (const float*)d_in[1];
  const float* ln1_b   = (const float*)d_in[2];
  const float* qkv_w   = (const float*)d_in[3];
  const float* qkv_b   = (const float*)d_in[4];
  const float* proj_w  = (const float*)d_in[5];
  const float* proj_b  = (const float*)d_in[6];
  const float* attn_g  = (const float*)d_in[7];
  const float* ln2_g   = (const float*)d_in[8];
  const float* ln2_b   = (const float*)d_in[9];
  const float* gat_w   = (const float*)d_in[10];
  const float* gat_b   = (const float*)d_in[11];
  const float* e_w1    = (const float*)d_in[12];
  const float* e_b1    = (const float*)d_in[13];
  const float* e_w2    = (const float*)d_in[14];
  const float* e_b2    = (const float*)d_in[15];
  float* out = (float*)d_out;

  char* p = (char*)d_ws;
  unsigned short* h    = (unsigned short*)p; p += (size_t)M_ * C_ * 2;      // 8 MB
  unsigned short* qkv  = (unsigned short*)p; p += (size_t)M_ * C3_ * 2;     // 24 MB
  unsigned short* Pb   = (unsigned short*)p; p += (size_t)M_ * C_ * 2;      // 8 MB
  unsigned short* aout = (unsigned short*)p; p += (size_t)M_ * C_ * 2;      // 8 MB
  float*          x1   = (float*)p;          p += (size_t)M_ * C_ * 4;      // 16 MB
  unsigned short* h2   = (unsigned short*)p; p += (size_t)M_ * C_ * 2;      // 8 MB
  float*          gts  = (float*)p;          p += (size_t)M_ * E_ * 4;      // 256 KB
  float*          S    = (float*)p;          p += (size_t)B_ * NCH_ * C_ * 4;
  unsigned short* wq   = (unsigned short*)p; p += (size_t)C3_ * C_ * 2;
  unsigned short* wp   = (unsigned short*)p; p += (size_t)C_ * C_ * 2;
  unsigned short* w1t  = (unsigned short*)p; p += (size_t)KH_ * C_ * 2;     // 2 MB [4096,256]
  unsigned char*  w2f8 = (unsigned char*)p;  p += (size_t)C_ * KH_;         // 1 MB [256,4096]
  unsigned char*  hid8 = (unsigned char*)p;  p += (size_t)M_ * KH_;         // 64 MB [M,4096]

  dim3 t32x8(32, 8);
  transpose_cvt<<<dim3(C3_/32, C_/32, 1), t32x8, 0, stream>>>(qkv_w, wq, C_, C3_, C_, 0);
  transpose_cvt<<<dim3(C_/32, C_/32, 1),  t32x8, 0, stream>>>(proj_w, wp, C_, C_, C_, 0);
  // w1t[e*1024 + hrow][c]  (flat [4096, 256]) bf16
  transpose_cvt<<<dim3(H_/32, C_/32, E_), t32x8, 0, stream>>>(e_w1, w1t, C_, H_, C_, (size_t)H_ * C_);
  // w2f8[c][perm(e*1024+h)] fp8 x256
  transpose_w2_fp8<<<dim3(H_/32, C_/32, E_), t32x8, 0, stream>>>(e_w2, w2f8);

  ln1_kernel<<<M_, 256, 0, stream>>>(x, ln1_g, ln1_b, h);
  gemm128<0><<<dim3(M_/128, C3_/128), 256, 0, stream>>>(h, wq, qkv_b, C_, C3_,
      nullptr, nullptr, qkv, nullptr, nullptr);
  scan1_kernel<<<B_*NCH_, 256, 0, stream>>>(qkv, S);
  scan2_kernel<<<B_, 256, 0, stream>>>(S);
  scan3_kernel<<<B_*NCH_, 256, 0, stream>>>(qkv, S, Pb);
  attn_kernel<<<M_/4, 256, 0, stream>>>(qkv, Pb, attn_g, aout);
  // x1 = x + aout @ proj_w + proj_b
  gemm128<1><<<dim3(M_/128, C_/128), 256, 0, stream>>>(aout, wp, proj_b, C_, C_,
      x, x1, nullptr, nullptr, nullptr);
  ln2_gates_kernel<<<M_, 256, 0, stream>>>(x1, ln2_g, ln2_b, gat_w, gat_b, h2, gts);
  // hid8 = fp8(64 * gate * gelu_s(h2 @ w1 + b1)), permuted columns
  gemm128<2><<<dim3(M_/128, KH_/128), 256, 0, stream>>>(h2, w1t, e_b1, C_, 0,
      nullptr, nullptr, nullptr, hid8, gts);
  // out = hid8 @ w2f8 / 2^14 + x1 + sum_e gate_e*b2_e
  gemm_down<<<dim3(M_/128, C_/64), 256, 0, stream>>>(hid8, w2f8, e_b2, gts, x1, out);
}